// Round 13
// baseline (120.935 us; speedup 1.0000x reference)
//
#include <hip/hip_runtime.h>

// N=100000, E=3200000, H=256, G=128.
// R19: unconditional dual-prefetch pipeline (ILP-vs-predication test).
// Evidence chain:
//  - R9/R10: global f32 atomics memory-side at ANY scope -> LDS agg only.
//  - R11: grid.sync ~50us -> no fusion; ~88us harness poison fills INSIDE
//    the timed window (fixed tax, independent of our ws usage).
//  - R16/R17: p1 ~ RNG x E dst-scan work; occupancy and work trade 1:1
//    (latency-hiding-limited); partial traffic minor.
//  - R18: hand pipeline w/ PREDICATED src loads: -1.6us only. Control-
//    dependent loads compile to divergent branches -> the 4 src loads can't
//    issue back-to-back; pipeline depth collapsed. Predication saves L2
//    requests but kills ILP - the two effects fight.
// This round: load 4 dst quads AND 4 src quads unconditionally, back-to-back
// (8 independent dwordx4 in flight, one waitcnt), then test+process. Wasted
// src quads (59%) are L2/L3 hits (R13/R15 FETCH evidence). Config = R15/R18:
// RNG=8, CHK=64, BLK1=1024, 2 blk/CU, 32 waves/CU.
//  P1: block (r,j) streams edge chunk j, filters dst in range r, LDS f32
//      atomics into acc, slab -> partial[r*CHK+j]. Block 0 zeroes header.
//  P2: a = sum_j partial[r][j][li], collapsed MLP, per-graph LDS pooling,
//      sparse device atomics, ticket epilogue -> relu(mean + b_out).

#define GMAX 128       // max graphs
#define HMAX 256       // max hidden dim
#define RNG  8         // node ranges (LDS-sized)
#define CHK  64        // edge chunks (%8==0 for XCD affinity; grid=512)
#define BLK1 1024      // p1 threads (16 waves; 2 blocks/CU = 32 waves = 100%)
#define RLDS 12544     // LDS accumulator words per range (>= ceil(N/RNG), %64==0)
#define HDRW 272       // header words (gsum,gcnt,done + pad to 16B)

// range-test a dst quad
#define RTEST(dd, ax, ay, az, aw)                               \
  ax = (unsigned)(dd.x - lo); ay = (unsigned)(dd.y - lo);       \
  az = (unsigned)(dd.z - lo); aw = (unsigned)(dd.w - lo);

// gather + LDS atomic for the passing lanes of a quad
#define RPROC(ss, ax, ay, az, aw)                               \
  if (ax < span) atomicAdd(&acc[ax], x[ss.x]);                  \
  if (ay < span) atomicAdd(&acc[ay], x[ss.y]);                  \
  if (az < span) atomicAdd(&acc[az], x[ss.z]);                  \
  if (aw < span) atomicAdd(&acc[aw], x[ss.w]);

// ---------------- main path ----------------

__global__ __launch_bounds__(BLK1, 8) void p1_scatter(
    const int* __restrict__ ei, const float* __restrict__ x,
    float* __restrict__ partial, float* __restrict__ gsum,
    float* __restrict__ gcnt, unsigned* __restrict__ done,
    int E, int N, int RANGE, int QpC) {
  __shared__ __align__(16) float acc[RLDS];
  int tid = threadIdx.x, blk = blockIdx.x;
  int r = blk / CHK;         // node range id   [0,RNG)
  int j = blk % CHK;         // edge chunk id   [0,CHK) -> XCD = j%8
  for (int i = tid; i < RLDS; i += BLK1) acc[i] = 0.f;
  if (blk == 0) {            // zero epilogue state for P2 (ws is poisoned)
    if (tid < GMAX) { gsum[tid] = 0.f; gcnt[tid] = 0.f; }
    if (tid == 0) done[0] = 0u;
  }
  __syncthreads();

  int lo = r * RANGE;
  unsigned span = (unsigned)(min(lo + RANGE, N) - lo);
  int Q = E >> 2;
  int q0 = j * QpC, q1 = min(q0 + QpC, Q);
  const int4* s4 = (const int4*)ei;
  const int4* d4 = (const int4*)(ei + E);

  int q = q0 + tid;
  // main: 8 independent dwordx4 loads in flight (no control-dependent loads)
  while (q + 3 * BLK1 < q1) {
    int4 d0 = d4[q];
    int4 d1 = d4[q + BLK1];
    int4 d2 = d4[q + 2 * BLK1];
    int4 d3 = d4[q + 3 * BLK1];
    int4 s0 = s4[q];
    int4 s1 = s4[q + BLK1];
    int4 s2 = s4[q + 2 * BLK1];
    int4 s3 = s4[q + 3 * BLK1];
    unsigned a0x, a0y, a0z, a0w, a1x, a1y, a1z, a1w;
    unsigned a2x, a2y, a2z, a2w, a3x, a3y, a3z, a3w;
    RTEST(d0, a0x, a0y, a0z, a0w)
    RTEST(d1, a1x, a1y, a1z, a1w)
    RTEST(d2, a2x, a2y, a2z, a2w)
    RTEST(d3, a3x, a3y, a3z, a3w)
    RPROC(s0, a0x, a0y, a0z, a0w)
    RPROC(s1, a1x, a1y, a1z, a1w)
    RPROC(s2, a2x, a2y, a2z, a2w)
    RPROC(s3, a3x, a3y, a3z, a3w)
    q += 4 * BLK1;
  }
  // remainder
  while (q < q1) {
    int4 d0 = d4[q];
    int4 s0 = s4[q];
    unsigned a0x, a0y, a0z, a0w;
    RTEST(d0, a0x, a0y, a0z, a0w)
    RPROC(s0, a0x, a0y, a0z, a0w)
    q += BLK1;
  }
  if (j == 0) {              // tail edges (E % 4): the RNG j==0 blocks filter
    for (int e = (Q << 2) + tid; e < E; e += BLK1) {
      unsigned u = (unsigned)(ei[E + e] - lo);
      if (u < span) atomicAdd(&acc[u], x[ei[e]]);
    }
  }
  __syncthreads();

  // coalesced slab dump (full RLDS incl zero pad; P2 reads only li < RANGE)
  float4* dst = (float4*)(partial + (size_t)blk * RLDS);
  const float4* a4 = (const float4*)acc;
  for (int i = tid; i < RLDS / 4; i += BLK1) dst[i] = a4[i];
}

__global__ __launch_bounds__(256, 4) void p2_node(
    const float* __restrict__ partial, const int* __restrict__ batch,
    const float* __restrict__ Wl, const float* __restrict__ bl,
    const float* __restrict__ Wo, const float* __restrict__ bo,
    float* __restrict__ gsum, float* __restrict__ gcnt,
    unsigned* __restrict__ done, float* __restrict__ out,
    int N, int H, int G, int RANGE, int BPR) {
  __shared__ float sWl[HMAX], sbl[HMAX], sWo[HMAX];
  __shared__ float ls[GMAX], lc[GMAX];
  __shared__ unsigned ticket;
  int tid = threadIdx.x, blk = blockIdx.x;
  if (tid < H) { sWl[tid] = Wl[tid]; sbl[tid] = bl[tid]; sWo[tid] = Wo[tid]; }
  if (tid < GMAX) { ls[tid] = 0.f; lc[tid] = 0.f; }
  __syncthreads();

  int r = blk / BPR;
  int li = (blk % BPR) * 256 + tid;
  int node = r * RANGE + li;
  if (li < RANGE && node < N) {
    // CHK-way partial sum: coalesced across lanes, 16-deep ILP across slabs
    const float* p = partial + (size_t)(r * CHK) * RLDS + li;
    float a = 0.f;
#pragma unroll 16
    for (int c = 0; c < CHK; ++c) a += p[(size_t)c * RLDS];
    float f = 0.f;
#pragma unroll 8
    for (int k = 0; k < H; ++k) {
      float hh = fmaf(a, sWl[k], sbl[k]);
      f = fmaf(fmaxf(hh, 0.f), sWo[k], f);
    }
    int g = batch[node];
    atomicAdd(&ls[g], f);
    atomicAdd(&lc[g], 1.f);
  }
  __syncthreads();
  if (tid < GMAX && lc[tid] != 0.f) {
    atomicAdd(&gsum[tid], ls[tid]);   // sparse: batch sorted -> ~1-2 graphs/blk
    atomicAdd(&gcnt[tid], lc[tid]);
  }
  __syncthreads();
  if (tid == 0)
    ticket = __hip_atomic_fetch_add(done, 1u, __ATOMIC_ACQ_REL,
                                    __HIP_MEMORY_SCOPE_AGENT);
  __syncthreads();
  if (ticket == gridDim.x - 1 && tid < G) {
    float s = __hip_atomic_load(&gsum[tid], __ATOMIC_RELAXED, __HIP_MEMORY_SCOPE_AGENT);
    float c = __hip_atomic_load(&gcnt[tid], __ATOMIC_RELAXED, __HIP_MEMORY_SCOPE_AGENT);
    out[tid] = fmaxf(s / fmaxf(c, 1.f) + bo[0], 0.f);
  }
}

// ---------------- fallback path (guards fail) ----------------

__global__ __launch_bounds__(256) void fb_scatter(const int* __restrict__ ei,
                                                  const float* __restrict__ x,
                                                  float* __restrict__ agg, int E) {
  int t = blockIdx.x * blockDim.x + threadIdx.x;
  if (t < E) atomicAdd(&agg[ei[E + t]], x[ei[t]]);
}

__global__ __launch_bounds__(256) void fb_node(const float* __restrict__ agg,
                                               const int* __restrict__ batch,
                                               const float* __restrict__ Wl,
                                               const float* __restrict__ bl,
                                               const float* __restrict__ Wo,
                                               float* __restrict__ gsum,
                                               float* __restrict__ gcnt, int N, int H) {
  __shared__ float sWl[HMAX], sbl[HMAX], sWo[HMAX];
  __shared__ float ls[GMAX], lc[GMAX];
  int tid = threadIdx.x;
  if (tid < H) { sWl[tid] = Wl[tid]; sbl[tid] = bl[tid]; sWo[tid] = Wo[tid]; }
  if (tid < GMAX) { ls[tid] = 0.f; lc[tid] = 0.f; }
  __syncthreads();
  int i = blockIdx.x * blockDim.x + tid;
  if (i < N) {
    float a = agg[i], f = 0.f;
    for (int k = 0; k < H; ++k) {
      float hh = fmaf(a, sWl[k], sbl[k]);
      f = fmaf(fmaxf(hh, 0.f), sWo[k], f);
    }
    int g = batch[i];
    atomicAdd(&ls[g], f);
    atomicAdd(&lc[g], 1.f);
  }
  __syncthreads();
  if (tid < GMAX && lc[tid] != 0.f) {
    atomicAdd(&gsum[tid], ls[tid]);
    atomicAdd(&gcnt[tid], lc[tid]);
  }
}

__global__ void fb_final(const float* __restrict__ gsum,
                         const float* __restrict__ gcnt,
                         const float* __restrict__ b_out,
                         float* __restrict__ out, int G) {
  int g = blockIdx.x * blockDim.x + threadIdx.x;
  if (g < G) out[g] = fmaxf(gsum[g] / fmaxf(gcnt[g], 1.f) + b_out[0], 0.f);
}

// ---------------- launch ----------------

extern "C" void kernel_launch(void* const* d_in, const int* in_sizes, int n_in,
                              void* d_out, int out_size, void* d_ws, size_t ws_size,
                              hipStream_t stream) {
  const float* x     = (const float*)d_in[0];
  const int*   ei    = (const int*)d_in[1];
  const int*   batch = (const int*)d_in[2];
  const float* Wl    = (const float*)d_in[3];
  const float* bl    = (const float*)d_in[4];
  const float* Wo    = (const float*)d_in[5];
  const float* bo    = (const float*)d_in[6];
  float* out = (float*)d_out;

  int N = in_sizes[0];        // 100000
  int E = in_sizes[1] / 2;    // 3200000
  int H = in_sizes[3];        // 256
  int G = out_size;           // 128

  int RANGE = (N + RNG - 1) / RNG;           // 12500
  int Q     = E >> 2;
  int QpC   = (Q + CHK - 1) / CHK;           // 12500 quads/chunk

  // ws layout (words): gsum[GMAX] | gcnt[GMAX] | done[..] | pad -> HDRW |
  //                    partial[RNG*CHK][RLDS]
  size_t need = ((size_t)HDRW + (size_t)RNG * CHK * RLDS) * 4u;

  if (RANGE <= RLDS && H <= HMAX && G <= GMAX && ws_size >= need && N > 0) {
    float*    w     = (float*)d_ws;
    float*    gsum  = w;
    float*    gcnt  = w + GMAX;
    unsigned* done  = (unsigned*)(w + 2 * GMAX);
    float*    partial = w + HDRW;

    p1_scatter<<<RNG * CHK, BLK1, 0, stream>>>(ei, x, partial, gsum, gcnt,
                                               done, E, N, RANGE, QpC);
    int BPR = (RANGE + 255) / 256;           // blocks per range (49)
    p2_node<<<RNG * BPR, 256, 0, stream>>>(partial, batch, Wl, bl, Wo, bo,
                                           gsum, gcnt, done, out,
                                           N, H, G, RANGE, BPR);
  } else {
    float* agg  = (float*)d_ws;
    float* gsum = agg + N;
    float* gcnt = gsum + GMAX;
    hipMemsetAsync(d_ws, 0, ((size_t)N + 2 * GMAX) * 4u, stream);
    fb_scatter<<<(E + 255) / 256, 256, 0, stream>>>(ei, x, agg, E);
    fb_node<<<(N + 255) / 256, 256, 0, stream>>>(agg, batch, Wl, bl, Wo,
                                                 gsum, gcnt, N, H);
    fb_final<<<1, 256, 0, stream>>>(gsum, gcnt, bo, out, G);
  }
}